// Round 1
// baseline (417.394 us; speedup 1.0000x reference)
//
#include <hip/hip_runtime.h>

typedef _Float16 half8 __attribute__((ext_vector_type(8)));
typedef _Float16 half4_t __attribute__((ext_vector_type(4)));
typedef float floatx16 __attribute__((ext_vector_type(16)));

#define NT 128
#define NB 64

// XOR swizzle within a 64-elem (128B) f16 row: spreads the 16-way bank
// pattern of stride-128B column reads. Bits 3..5 of the element index.
__device__ __forceinline__ int swz(int row) {
  return ((row & 7) << 3) ^ ((row & 24) << 1);
}

__global__ __launch_bounds__(512, 2)
void qrnn_fused(const float* __restrict__ data_r,
                const float* __restrict__ data_i,
                const float* __restrict__ U_r,
                const float* __restrict__ U_i,
                const float* __restrict__ lam_p,
                float* __restrict__ out) {
  const int b     = blockIdx.x;
  const int tid   = threadIdx.x;
  const int lane  = tid & 63;
  const int w     = tid >> 6;
  const int group = w >> 2;        // 0: real part, 1: imag part
  const int ph    = (w >> 1) & 1;  // U row-block owned (stage1 p-rows, stage2 rr-rows)
  const int rh    = w & 1;         // output col-block (stage1 r-cols, stage2 p-cols)

  // v^T [r][q], t [p][r], hhat [q][r]  (all f16, swizzled addressing)
  __shared__ __align__(16) _Float16 Vr[4096], Vi[4096];
  __shared__ __align__(16) _Float16 Tr[4096], Ti[4096];
  __shared__ __align__(16) _Float16 Hr[4096], Hi[4096];
  __shared__ float red[8];

  const float g = 1.0f / (1.0f + expf(-lam_p[0]));

  // ---- U fragments (A-operand layout: row = lane&31, k = 8*(lane>>5)+e), rows 32*ph.. ----
  // hi = f16(U), lo = f16((U - hi) * 256): fold later as acc_hi + acc_lo/256
  half8 aUrh[4], aUrl[4], aUih[4], aUil[4];
  {
    const int row = 32 * ph + (lane & 31);
    #pragma unroll
    for (int kq = 0; kq < 4; ++kq) {
      const int c0 = 16 * kq + 8 * (lane >> 5);
      #pragma unroll
      for (int e = 0; e < 8; ++e) {
        const float ur = U_r[row * 64 + c0 + e];
        const float ui = U_i[row * 64 + c0 + e];
        _Float16 h;
        h = (_Float16)ur; aUrh[kq][e] = h; aUrl[kq][e] = (_Float16)((ur - (float)h) * 256.0f);
        h = (_Float16)ui; aUih[kq][e] = h; aUil[kq][e] = (_Float16)((ui - (float)h) * 256.0f);
      }
    }
  }

  // ---- init state: hhat0 = I/64, S = 1 ----
  for (int idx = tid; idx < 4096; idx += 512) {
    const int q = idx >> 6, r = idx & 63;
    const int off = q * 64 + (r ^ swz(q));
    Hr[off] = (q == r) ? (_Float16)(1.0f / 64.0f) : (_Float16)0.0f;
    Hi[off] = (_Float16)0.0f;
  }
  float S = 1.0f;

  // ---- prefetch x_0 ----
  float xr[8], xi[8];
  {
    const size_t xb = (size_t)b * 4096;
    #pragma unroll
    for (int it = 0; it < 2; ++it) {
      const int q = (tid >> 4) + 32 * it;
      const int m = tid & 15;
      #pragma unroll
      for (int j = 0; j < 4; ++j) {
        const int r = m + 16 * j;
        xr[it * 4 + j] = data_r[xb + q * 64 + r];
        xi[it * 4 + j] = data_i[xb + q * 64 + r];
      }
    }
  }
  __syncthreads();

  for (int t = 0; t < NT; ++t) {
    // ================= MIX: out_{t-1} = S*hhat ; vhat = g*hhat + ((1-g)/S)*x_t =================
    const float kap = (1.0f - g) / S;
    #pragma unroll
    for (int it = 0; it < 2; ++it) {
      const int q = (tid >> 4) + 32 * it;
      const int m = tid & 15;
      #pragma unroll
      for (int j = 0; j < 4; ++j) {
        const int r = m + 16 * j;
        const int hoff = q * 64 + (r ^ swz(q));
        const float hr = (float)Hr[hoff];
        const float hi = (float)Hi[hoff];
        if (t > 0) {
          const size_t ob = ((size_t)(t - 1) * NB + b) * 4096 + (size_t)(q * 64 + r);
          out[ob] = S * hr;
          out[ob + (size_t)NT * NB * 4096] = S * hi;
        }
        const int voff = r * 64 + (q ^ swz(r));
        Vr[voff] = (_Float16)(g * hr + kap * xr[it * 4 + j]);
        Vi[voff] = (_Float16)(g * hi + kap * xi[it * 4 + j]);
      }
    }
    // prefetch x_{t+1} (lands during MFMA phases)
    {
      const int tn = (t + 1 < NT) ? (t + 1) : t;
      const size_t xb = ((size_t)tn * NB + b) * 4096;
      #pragma unroll
      for (int it = 0; it < 2; ++it) {
        const int q = (tid >> 4) + 32 * it;
        const int m = tid & 15;
        #pragma unroll
        for (int j = 0; j < 4; ++j) {
          const int r = m + 16 * j;
          xr[it * 4 + j] = data_r[xb + q * 64 + r];
          xi[it * 4 + j] = data_i[xb + q * 64 + r];
        }
      }
    }
    __syncthreads();

    // ================= STAGE 1: t = U @ v  (t_r = Ur vr - Ui vi ; t_i = Ur vi + Ui vr) =========
    {
      half8 b1[4], b2[4];
      const int r  = 32 * rh + (lane & 31);   // B col = r
      const int cb = 8 * (lane >> 5);
      const int sz = swz(r);
      #pragma unroll
      for (int kq = 0; kq < 4; ++kq) {
        const int off = r * 64 + ((16 * kq + cb) ^ sz);
        const half8 bvr = *reinterpret_cast<const half8*>(&Vr[off]);
        const half8 bvi = *reinterpret_cast<const half8*>(&Vi[off]);
        if (group == 0) { b1[kq] = bvr; b2[kq] = -bvi; }
        else            { b1[kq] = bvi; b2[kq] = bvr;  }
      }
      floatx16 acch, accl;
      #pragma unroll
      for (int j = 0; j < 16; ++j) { acch[j] = 0.0f; accl[j] = 0.0f; }
      #pragma unroll
      for (int kq = 0; kq < 4; ++kq) {
        acch = __builtin_amdgcn_mfma_f32_32x32x16_f16(aUrh[kq], b1[kq], acch, 0, 0, 0);
        acch = __builtin_amdgcn_mfma_f32_32x32x16_f16(aUih[kq], b2[kq], acch, 0, 0, 0);
        accl = __builtin_amdgcn_mfma_f32_32x32x16_f16(aUrl[kq], b1[kq], accl, 0, 0, 0);
        accl = __builtin_amdgcn_mfma_f32_32x32x16_f16(aUil[kq], b2[kq], accl, 0, 0, 0);
      }
      _Float16* Tg = group ? Ti : Tr;
      #pragma unroll
      for (int j = 0; j < 16; ++j) {
        const float tv = acch[j] + accl[j] * (1.0f / 256.0f);
        const int p = 32 * ph + (j & 3) + 8 * (j >> 2) + 4 * (lane >> 5);
        Tg[p * 64 + (r ^ swz(p))] = (_Float16)tv;
      }
    }
    __syncthreads();

    // ====== STAGE 2 (transposed): h'^T[rr][p] ; h'_r = t_r UrT + t_i UiT ; h'_i = t_i UrT - t_r UiT
    float rv[16];
    {
      half8 b1[4], b2[4];
      const int p  = 32 * rh + (lane & 31);   // B col = p
      const int cb = 8 * (lane >> 5);
      const int sz = swz(p);
      #pragma unroll
      for (int kq = 0; kq < 4; ++kq) {
        const int off = p * 64 + ((16 * kq + cb) ^ sz);
        const half8 btr = *reinterpret_cast<const half8*>(&Tr[off]);
        const half8 bti = *reinterpret_cast<const half8*>(&Ti[off]);
        if (group == 0) { b1[kq] = btr; b2[kq] = bti;  }
        else            { b1[kq] = bti; b2[kq] = -btr; }
      }
      floatx16 acch, accl;
      #pragma unroll
      for (int j = 0; j < 16; ++j) { acch[j] = 0.0f; accl[j] = 0.0f; }
      #pragma unroll
      for (int kq = 0; kq < 4; ++kq) {
        acch = __builtin_amdgcn_mfma_f32_32x32x16_f16(aUrh[kq], b1[kq], acch, 0, 0, 0);
        acch = __builtin_amdgcn_mfma_f32_32x32x16_f16(aUih[kq], b2[kq], acch, 0, 0, 0);
        accl = __builtin_amdgcn_mfma_f32_32x32x16_f16(aUrl[kq], b1[kq], accl, 0, 0, 0);
        accl = __builtin_amdgcn_mfma_f32_32x32x16_f16(aUil[kq], b2[kq], accl, 0, 0, 0);
      }
      #pragma unroll
      for (int j = 0; j < 16; ++j) rv[j] = acch[j] + accl[j] * (1.0f / 256.0f);
    }

    // ================= RESCALE: alpha = 2^-E keeps max|hhat| in [0.5,1) ====================
    float mloc = 0.0f;
    #pragma unroll
    for (int j = 0; j < 16; ++j) mloc = fmaxf(mloc, fabsf(rv[j]));
    #pragma unroll
    for (int d = 32; d >= 1; d >>= 1) mloc = fmaxf(mloc, __shfl_xor(mloc, d, 64));
    if (lane == 0) red[w] = mloc;
    __syncthreads();
    float mm = red[0];
    #pragma unroll
    for (int i = 1; i < 8; ++i) mm = fmaxf(mm, red[i]);
    int E = 0;
    if (mm > 0.0f) frexpf(mm, &E);
    const float alpha = ldexpf(1.0f, -E);
    S = S * ldexpf(1.0f, E);

    // ================= write hhat_t = alpha * rv =================
    {
      _Float16* Hg = group ? Hi : Hr;
      const int p  = 32 * rh + (lane & 31);
      const int sz = swz(p);
      #pragma unroll
      for (int jj = 0; jj < 4; ++jj) {
        half4_t hv;
        #pragma unroll
        for (int e = 0; e < 4; ++e) hv[e] = (_Float16)(alpha * rv[4 * jj + e]);
        const int rr0 = 32 * ph + 8 * jj + 4 * (lane >> 5);
        *reinterpret_cast<half4_t*>(&Hg[p * 64 + (rr0 ^ sz)]) = hv;
      }
    }
    __syncthreads();
  }

  // ---- epilogue: out_{T-1} ----
  #pragma unroll
  for (int it = 0; it < 2; ++it) {
    const int q = (tid >> 4) + 32 * it;
    const int m = tid & 15;
    #pragma unroll
    for (int j = 0; j < 4; ++j) {
      const int r = m + 16 * j;
      const int hoff = q * 64 + (r ^ swz(q));
      const size_t ob = ((size_t)(NT - 1) * NB + b) * 4096 + (size_t)(q * 64 + r);
      out[ob] = S * (float)Hr[hoff];
      out[ob + (size_t)NT * NB * 4096] = S * (float)Hi[hoff];
    }
  }
}

extern "C" void kernel_launch(void* const* d_in, const int* in_sizes, int n_in,
                              void* d_out, int out_size, void* d_ws, size_t ws_size,
                              hipStream_t stream) {
  (void)in_sizes; (void)n_in; (void)out_size; (void)d_ws; (void)ws_size;
  qrnn_fused<<<dim3(NB), dim3(512), 0, stream>>>(
      (const float*)d_in[0], (const float*)d_in[1],
      (const float*)d_in[2], (const float*)d_in[3],
      (const float*)d_in[4], (float*)d_out);
}